// Round 6
// baseline (370.541 us; speedup 1.0000x reference)
//
#include <hip/hip_runtime.h>

// DeltaQuantLinear: out[t,o] = sum_k x[t,k] * (base[o,k] + (q[o,k]-zp[o])*scale[o]) + bias[o]
// M=8 tokens, N=11008 out rows, K=4096. Memory-bound: 361 MB weights+q per call.
//
// R6 = MEASUREMENT ROUND. R2..R5 (four different structures) all bench 337-357us
// and the kernel never appears in top-5 (hidden under ~105us harness fills), so
// its counters have never been observed. This round repeats the R5 body 4x
// inside one dispatch (identical work+output each rep) to force the kernel into
// the top-5 profile and to expose per-rep time via dur_us = fixed + 4k.

#define IN_F    4096
#define OUT_F   11008
#define TOKENS  8
#define RPB     2                 // output rows per block
#define THREADS 256
#define NBLOCKS (OUT_F / RPB)     // 5504
#define REPS    4                 // measurement: x4 identical passes

typedef float vf4 __attribute__((ext_vector_type(4)));
typedef int   vi4 __attribute__((ext_vector_type(4)));

__global__ __launch_bounds__(THREADS, 2)
void DeltaQuantLinear_87540023427416_kernel(
    const float* __restrict__ x,      // [8, 4096]
    const float* __restrict__ w,      // [11008, 4096]
    const int*   __restrict__ q,      // [11008, 4096]
    const float* __restrict__ scales, // [11008]
    const float* __restrict__ zps,    // [11008]
    const float* __restrict__ bias,   // [11008]
    float*       __restrict__ out)    // [8, 11008]
{
    // 57,344 B: pins 2 blocks/CU. red = [16][257] stride-257 (conflict-free).
    __shared__ float lds[14336];
    float* red  = lds;
    float* red2 = lds + 16 * 257; // [16][16]

    const int tid = threadIdx.x;
    const int o0  = blockIdx.x * RPB;

    float s[RPB], c0[RPB];
#pragma unroll
    for (int r = 0; r < RPB; ++r) {
        const float sc = scales[o0 + r];
        s[r]  = sc;
        c0[r] = -zps[o0 + r] * sc;   // (q - zp)*s = q*s + c0
    }

    const float* wbase = w + (size_t)o0 * IN_F + tid * 4;
    const int*   qbase = q + (size_t)o0 * IN_F + tid * 4;

#pragma unroll 1
    for (int rep = 0; rep < REPS; ++rep) {
        float acc[RPB][TOKENS];
#pragma unroll
        for (int r = 0; r < RPB; ++r)
#pragma unroll
            for (int t = 0; t < TOKENS; ++t) acc[r][t] = 0.0f;

        vf4 wv[2][RPB];
        vi4 qv[2][RPB];

        // prefetch chunk 0 wq (nontemporal streaming)
#pragma unroll
        for (int r = 0; r < RPB; ++r) {
            wv[0][r] = __builtin_nontemporal_load((const vf4*)(wbase + (size_t)r * IN_F));
            qv[0][r] = __builtin_nontemporal_load((const vi4*)(qbase + (size_t)r * IN_F));
        }

#pragma unroll
        for (int c = 0; c < 4; ++c) {
            const int cur = c & 1;
            const int nxt = cur ^ 1;
            const int kbase = c * 1024 + tid * 4;

            // 1) x loads for THIS chunk (L2-resident)
            vf4 xr[TOKENS];
#pragma unroll
            for (int t = 0; t < TOKENS; ++t)
                xr[t] = *(const vf4*)(x + t * IN_F + kbase);

            // 2) next chunk's wq prefetch stays in flight through the FMA body
            if (c < 3) {
                const int koff = (c + 1) * 1024;
#pragma unroll
                for (int r = 0; r < RPB; ++r) {
                    wv[nxt][r] = __builtin_nontemporal_load((const vf4*)(wbase + (size_t)r * IN_F + koff));
                    qv[nxt][r] = __builtin_nontemporal_load((const vi4*)(qbase + (size_t)r * IN_F + koff));
                }
            }

            // 3) compute chunk c
#pragma unroll
            for (int r = 0; r < RPB; ++r) {
#pragma unroll
                for (int j = 0; j < 4; ++j) {
                    const float wfull = fmaf((float)qv[cur][r][j], s[r], wv[cur][r][j] + c0[r]);
#pragma unroll
                    for (int t = 0; t < TOKENS; ++t)
                        acc[r][t] = fmaf(xr[t][j], wfull, acc[r][t]);
                }
            }
        }

        // Block reduction: 16 outputs (2 rows x 8 tokens), 256 partials each.
#pragma unroll
        for (int r = 0; r < RPB; ++r)
#pragma unroll
            for (int t = 0; t < TOKENS; ++t)
                red[(r * 8 + t) * 257 + tid] = acc[r][t];
        __syncthreads();

        {   // 16 threads per output, each sums 16 partials (conflict-free)
            const int l = tid & 15;
            const int p = tid >> 4;
            float sum = 0.0f;
            const float* row = &red[l * 257 + p * 16];
#pragma unroll
            for (int j = 0; j < 16; ++j) sum += row[j];
            red2[l * 16 + p] = sum;
        }
        __syncthreads();

        if (tid < 16) {
            float tot = 0.0f;
#pragma unroll
            for (int j = 0; j < 16; ++j) tot += red2[tid * 16 + j];
            const int r = tid >> 3;
            const int t = tid & 7;
            const int o = o0 + r;
            out[t * OUT_F + o] = tot + bias[o];
        }
        __syncthreads();   // protect red[] before next rep overwrites
    }
}

extern "C" void kernel_launch(void* const* d_in, const int* in_sizes, int n_in,
                              void* d_out, int out_size, void* d_ws, size_t ws_size,
                              hipStream_t stream) {
    const float* x      = (const float*)d_in[0];
    const float* w      = (const float*)d_in[1];
    const int*   q      = (const int*)d_in[2];
    const float* scales = (const float*)d_in[3];
    const float* zps    = (const float*)d_in[4];
    const float* bias   = (const float*)d_in[5];
    float* out = (float*)d_out;

    DeltaQuantLinear_87540023427416_kernel<<<NBLOCKS, THREADS, 0, stream>>>(
        x, w, q, scales, zps, bias, out);
}